// Round 11
// baseline (26.789 us; speedup 1.0000x reference)
//
#include <hip/hip_runtime.h>
#include <math.h>

#define STRIDE_F 8.0f
#define N_CLS 80
#define NA 3
#define NCH (5 + N_CLS)   // 85
#define NG 64
#define NGT 50
#define NANCH 9
#define EPS_T 1e-8f
#define MAIN_BLOCKS 48    // 48 blocks * 256 thr * 1 cell = NA*NG*NG per batch

__device__ __forceinline__ float bce_logits(float x, float t) {
    return fmaxf(x, 0.0f) - x * t + log1pf(expf(-fabsf(x)));
}

// Single dispatch, grid = (MAIN_BLOCKS, nB). Worker math identical to R9.
// Tail: after storing its partial, each block's thread 0 does one
// fetch_add(ACQ_REL, AGENT) on a monotonically-growing counter. The block
// whose increment is the nWork-th of this replay ((old+1) % nWork == 0 --
// correct from ANY initial counter value, so 0xAA poison and accumulation
// across replays are harmless) becomes the finisher: it sums the 768
// partials in fixed ascending order (bitwise-deterministic) and writes out.
// No spinning, no flags, no second dispatch.
__global__ __launch_bounds__(256) void fcos_fused(
        const float* __restrict__ raw,
        const float* __restrict__ labels,
        const float* __restrict__ all_anchors,
        const int* __restrict__ anchor_indices,
        const int* __restrict__ img_size,
        float* __restrict__ partials,
        unsigned int* __restrict__ counter,
        float* __restrict__ out,
        int nWork) {
    __shared__ float4 s_box[NGT];   // corner box (xl,yt,xr,yb)
    __shared__ float4 s_tl[NGT];    // target ltrb logs
    __shared__ float2 s_tk[NGT];    // (0.375*areaG, key-as-float-bits)
    __shared__ int    s_key[NGT];
    __shared__ float  s_wv[NGT];
    __shared__ int    s_cls[NGT];
    __shared__ int    s_win[NGT];
    __shared__ int    s_any;
    __shared__ float  swave[4];
    __shared__ int    s_last;

    int tid = threadIdx.x;
    int b  = blockIdx.y;
    int bx = blockIdx.x;
    int flat = b * MAIN_BLOCKS + bx;
    float fimg = (float)(*img_size);

    // ---- issue the 5 scalar loads first (latency hides under prep) ---------
    int cp = bx * 256 + tid;   // flat cell id == (a<<12)|(y<<6)|x
    int a = cp >> 12;
    int y = (cp >> 6) & (NG - 1);
    int x0 = cp & (NG - 1);
    const float* rb = raw + ((size_t)(b * (NA * NCH) + a * NCH) << 12)
                          + (y << 6) + x0;
    float r0 = rb[0];
    float r1 = rb[1 * 4096];
    float r2 = rb[2 * 4096];
    float r3 = rb[3 * 4096];
    float r4 = rb[4 * 4096];

    // ---------------- per-block GT prep (threads 0..49, wave 0) -------------
    int valid = 0, key = -1, bn = 0;
    float gx = 0, gy = 0, gw = 0, gh = 0, cls = 0;
    if (tid < NGT) {
        const float* lab = labels + (b * NGT + tid) * 5;
        cls = lab[0];
        gx = lab[1]; gy = lab[2]; gw = lab[3]; gh = lab[4];
        int best = 0; float bi = -1.0f;
        for (int k = 0; k < NANCH; ++k) {
            float aw = all_anchors[2 * k], ah = all_anchors[2 * k + 1];
            float inter = fminf(gw, aw) * fminf(gh, ah);
            float iou = inter / (gw * gh + aw * ah - inter);
            if (iou > bi) { bi = iou; best = k; }
        }
        bn = best % NA;
        for (int j = 0; j < NA; ++j) if (anchor_indices[j] == best) valid = 1;
        int ti = (int)(gx / STRIDE_F);
        int tj = (int)(gy / STRIDE_F);
        key = valid ? ((bn << 12) | (tj << 6) | ti) : -1;
        s_key[tid] = key;
    }
    __syncthreads();
    if (tid < NGT) {
        // JAX scatter "last valid update wins"
        int winner = valid;
        for (int gp = tid + 1; gp < NGT; ++gp)
            if (s_key[gp] == key) winner = 0;

        int ai = anchor_indices[bn];
        float aw = all_anchors[2 * ai], ah = all_anchors[2 * ai + 1];
        float ccx = (floorf(gx / STRIDE_F) + 0.5f) * STRIDE_F;
        float ccy = (floorf(gy / STRIDE_F) + 0.5f) * STRIDE_F;
        float l   = fmaxf(ccx - (gx - gw * 0.5f), 0.0f);
        float t   = fmaxf(ccy - (gy - gh * 0.5f), 0.0f);
        float r   = fmaxf(gx + gw * 0.5f - ccx, 0.0f);
        float btm = fmaxf(gy + gh * 0.5f - ccy, 0.0f);

        s_box[tid] = make_float4(gx - gw * 0.5f, gy - gh * 0.5f,
                                 gx + gw * 0.5f, gy + gh * 0.5f);
        s_tk[tid]  = make_float2(0.375f * (gw * gh), __int_as_float(key));
        s_tl[tid]  = make_float4(logf(l / aw + EPS_T), logf(t / ah + EPS_T),
                                 logf(r / aw + EPS_T), logf(btm / ah + EPS_T));
        s_wv[tid]  = 2.0f - gw * gh / fimg / fimg;
        s_cls[tid] = (int)cls;
        s_win[tid] = winner;
    }
    unsigned long long m = __ballot(valid != 0);   // wave 0 holds all GT lanes
    if (tid == 0) s_any = (m != 0ULL);
    __syncthreads();

    // ---- issue class-loss gather now; consumed after the 50-GT loop --------
    float cv1 = 0.0f, ct1 = 0.0f;
    bool cd1 = false;
    if (cp < NGT * N_CLS) {
        int g = cp / N_CLS;
        int cc = cp - g * N_CLS;
        if (s_win[g]) {
            int k = s_key[g];
            cv1 = *(raw + ((size_t)(b * (NA * NCH) + (k >> 12) * NCH + 5 + cc) << 12)
                        + (k & 0xFFF));
            ct1 = (cc == s_cls[g]) ? 1.0f : 0.0f;
            cd1 = true;
        }
    }

    // ---------------- main: 1 cell per thread -------------------------------
    int ai = anchor_indices[a];
    float aw = all_anchors[2 * ai], ah = all_anchors[2 * ai + 1];

    float lp = fminf(expf(r0) * aw, fimg);
    float tp = fminf(expf(r1) * ah, fimg);
    float rp = fminf(expf(r2) * aw, fimg);
    float bp = fminf(expf(r3) * ah, fimg);
    float px = ((float)x0 + 0.5f) * STRIDE_F + (rp - lp) * 0.5f;
    float py = ((float)y + 0.5f) * STRIDE_F + (bp - tp) * 0.5f;
    float pw = lp + rp, ph = tp + bp;
    float base = 0.375f * (pw * ph + 1e-12f);
    float pxl = px - pw * 0.5f, pxr = px + pw * 0.5f;
    float pyt = py - ph * 0.5f, pyb = py + ph * 0.5f;

    // iou >= 0.6  <=>  inter >= 0.375*(areaP+1e-12) + 0.375*areaG
    float maxd = -1e30f;
    int win = -1;
    #pragma unroll 10
    for (int g = 0; g < NGT; ++g) {
        float4 bb = s_box[g];
        float2 tk = s_tk[g];
        float tlx = fmaxf(pxl, bb.x);
        float tly = fmaxf(pyt, bb.y);
        float brx = fminf(pxr, bb.z);
        float bry = fminf(pyb, bb.w);
        float dx = fmaxf(brx - tlx, 0.0f);
        float dy = fmaxf(bry - tly, 0.0f);
        maxd = fmaxf(maxd, fmaf(dx, dy, -tk.x));
        if (__float_as_int(tk.y) == cp) win = g;   // ascending g: last wins
    }

    float loss = 0.0f;
    bool any_v = (s_any != 0);
    if (win >= 0) {
        loss += bce_logits(r4, 1.0f);
        float4 tl = s_tl[win];
        float wv = s_wv[win];
        float d0 = r0 - tl.x, d1 = r1 - tl.y, d2 = r2 - tl.z, d3 = r3 - tl.w;
        loss += 0.5f * wv * (d0 * d0 + d1 * d1 + d2 * d2 + d3 * d3);
    } else if (!any_v || maxd < base) {
        loss += bce_logits(r4, 0.0f);
    }

    // ---------------- class BCE on prefetched value -------------------------
    if (cd1) loss += bce_logits(cv1, ct1);

    // ---------------- block reduction -> partial ----------------------------
    for (int off = 32; off > 0; off >>= 1)
        loss += __shfl_down(loss, off, 64);
    if ((tid & 63) == 0) swave[tid >> 6] = loss;
    __syncthreads();
    if (tid == 0) {
        partials[flat] = swave[0] + swave[1] + swave[2] + swave[3];
        // release my partial + acquire everyone else's if I'm the last
        unsigned int old = __hip_atomic_fetch_add(counter, 1u,
                                                  __ATOMIC_ACQ_REL,
                                                  __HIP_MEMORY_SCOPE_AGENT);
        s_last = ((old + 1u) % (unsigned)nWork == 0u);
    }
    __syncthreads();

    // ---------------- last-arriving block sums all partials -----------------
    if (s_last) {
        float v = 0.0f;
        for (int i = tid; i < nWork; i += 256) v += partials[i];
        for (int off = 32; off > 0; off >>= 1)
            v += __shfl_down(v, off, 64);
        if ((tid & 63) == 0) swave[tid >> 6] = v;
        __syncthreads();
        if (tid == 0) out[0] = swave[0] + swave[1] + swave[2] + swave[3];
    }
}

extern "C" void kernel_launch(void* const* d_in, const int* in_sizes, int n_in,
                              void* d_out, int out_size, void* d_ws, size_t ws_size,
                              hipStream_t stream) {
    const float* raw            = (const float*)d_in[0];
    const float* labels         = (const float*)d_in[1];
    const float* all_anchors    = (const float*)d_in[2];
    const int*   anchor_indices = (const int*)d_in[3];
    const int*   img_size       = (const int*)d_in[4];
    float* out = (float*)d_out;

    int nB = in_sizes[0] / (NA * NCH * NG * NG);   // 16
    int nWork = nB * MAIN_BLOCKS;                  // 768

    float*        partials = (float*)d_ws;
    unsigned int* counter  = (unsigned int*)((char*)d_ws + 4096);

    fcos_fused<<<dim3(MAIN_BLOCKS, nB), 256, 0, stream>>>(
        raw, labels, all_anchors, anchor_indices, img_size,
        partials, counter, out, nWork);
}

// Round 12
// 16.225 us; speedup vs baseline: 1.6511x; 1.6511x over previous
//
#include <hip/hip_runtime.h>
#include <math.h>

#define STRIDE_F 8.0f
#define N_CLS 80
#define NA 3
#define NCH (5 + N_CLS)   // 85
#define NG 64
#define NGT 50
#define NANCH 9
#define EPS_T 1e-8f
#define MAIN_BLOCKS 48    // 48 blocks * 256 thr * 1 cell = NA*NG*NG

__device__ __forceinline__ float bce_logits(float x, float t) {
    return fmaxf(x, 0.0f) - x * t + log1pf(expf(-fabsf(x)));
}

// grid = (MAIN_BLOCKS, nB). Each block redundantly computes per-GT prep into
// LDS (one wave), each thread owns ONE cell (scalar loads, max TLP).
// Partials to ws; tiny reduce kernel sums 768 partials to out.
// NOTE (R10/R11 lessons): device-side cross-XCD sync (spin-flags or
// agent-scope ACQ_REL counter) costs +5..+10us on gfx950 -- the second
// dispatch node (~2.6us) is strictly cheaper. Keep the 2-dispatch structure.
__global__ __launch_bounds__(256) void fcos_fused(
        const float* __restrict__ raw,
        const float* __restrict__ labels,
        const float* __restrict__ all_anchors,
        const int* __restrict__ anchor_indices,
        const int* __restrict__ img_size,
        float* __restrict__ partials) {
    __shared__ float4 s_box[NGT];   // corner box (xl,yt,xr,yb)
    __shared__ float4 s_tl[NGT];    // target ltrb logs
    __shared__ float2 s_tk[NGT];    // (0.375*areaG, key-as-float-bits)
    __shared__ int    s_key[NGT];
    __shared__ float  s_wv[NGT];
    __shared__ int    s_cls[NGT];
    __shared__ int    s_win[NGT];
    __shared__ int    s_any;
    __shared__ float  swave[4];

    int b = blockIdx.y;
    int tid = threadIdx.x;
    float fimg = (float)(*img_size);

    // ---- issue the 5 scalar loads first (latency hides under prep) ---------
    int cp = blockIdx.x * 256 + tid;   // flat cell id == (a<<12)|(y<<6)|x
    int a = cp >> 12;
    int y = (cp >> 6) & (NG - 1);
    int x0 = cp & (NG - 1);
    const float* rb = raw + ((size_t)(b * (NA * NCH) + a * NCH) << 12)
                          + (y << 6) + x0;
    float r0 = rb[0];
    float r1 = rb[1 * 4096];
    float r2 = rb[2 * 4096];
    float r3 = rb[3 * 4096];
    float r4 = rb[4 * 4096];

    // ---------------- per-block GT prep (threads 0..49, wave 0) -------------
    int valid = 0, key = -1, bn = 0;
    float gx = 0, gy = 0, gw = 0, gh = 0, cls = 0;
    if (tid < NGT) {
        const float* lab = labels + (b * NGT + tid) * 5;
        cls = lab[0];
        gx = lab[1]; gy = lab[2]; gw = lab[3]; gh = lab[4];
        int best = 0; float bi = -1.0f;
        for (int k = 0; k < NANCH; ++k) {
            float aw = all_anchors[2 * k], ah = all_anchors[2 * k + 1];
            float inter = fminf(gw, aw) * fminf(gh, ah);
            float iou = inter / (gw * gh + aw * ah - inter);
            if (iou > bi) { bi = iou; best = k; }
        }
        bn = best % NA;
        for (int j = 0; j < NA; ++j) if (anchor_indices[j] == best) valid = 1;
        int ti = (int)(gx / STRIDE_F);
        int tj = (int)(gy / STRIDE_F);
        key = valid ? ((bn << 12) | (tj << 6) | ti) : -1;
        s_key[tid] = key;
    }
    __syncthreads();
    if (tid < NGT) {
        // JAX scatter "last valid update wins"
        int winner = valid;
        for (int gp = tid + 1; gp < NGT; ++gp)
            if (s_key[gp] == key) winner = 0;

        int ai = anchor_indices[bn];
        float aw = all_anchors[2 * ai], ah = all_anchors[2 * ai + 1];
        float ccx = (floorf(gx / STRIDE_F) + 0.5f) * STRIDE_F;
        float ccy = (floorf(gy / STRIDE_F) + 0.5f) * STRIDE_F;
        float l   = fmaxf(ccx - (gx - gw * 0.5f), 0.0f);
        float t   = fmaxf(ccy - (gy - gh * 0.5f), 0.0f);
        float r   = fmaxf(gx + gw * 0.5f - ccx, 0.0f);
        float btm = fmaxf(gy + gh * 0.5f - ccy, 0.0f);

        s_box[tid] = make_float4(gx - gw * 0.5f, gy - gh * 0.5f,
                                 gx + gw * 0.5f, gy + gh * 0.5f);
        s_tk[tid]  = make_float2(0.375f * (gw * gh), __int_as_float(key));
        s_tl[tid]  = make_float4(logf(l / aw + EPS_T), logf(t / ah + EPS_T),
                                 logf(r / aw + EPS_T), logf(btm / ah + EPS_T));
        s_wv[tid]  = 2.0f - gw * gh / fimg / fimg;
        s_cls[tid] = (int)cls;
        s_win[tid] = winner;
    }
    unsigned long long m = __ballot(valid != 0);   // wave 0 holds all GT lanes
    if (tid == 0) s_any = (m != 0ULL);
    __syncthreads();

    // ---- issue class-loss gather now; consumed after the 50-GT loop --------
    float cv1 = 0.0f, ct1 = 0.0f;
    bool cd1 = false;
    if (cp < NGT * N_CLS) {
        int g = cp / N_CLS;
        int cc = cp - g * N_CLS;
        if (s_win[g]) {
            int k = s_key[g];
            cv1 = *(raw + ((size_t)(b * (NA * NCH) + (k >> 12) * NCH + 5 + cc) << 12)
                        + (k & 0xFFF));
            ct1 = (cc == s_cls[g]) ? 1.0f : 0.0f;
            cd1 = true;
        }
    }

    // ---------------- main: 1 cell per thread -------------------------------
    int ai = anchor_indices[a];
    float aw = all_anchors[2 * ai], ah = all_anchors[2 * ai + 1];

    float lp = fminf(expf(r0) * aw, fimg);
    float tp = fminf(expf(r1) * ah, fimg);
    float rp = fminf(expf(r2) * aw, fimg);
    float bp = fminf(expf(r3) * ah, fimg);
    float px = ((float)x0 + 0.5f) * STRIDE_F + (rp - lp) * 0.5f;
    float py = ((float)y + 0.5f) * STRIDE_F + (bp - tp) * 0.5f;
    float pw = lp + rp, ph = tp + bp;
    float base = 0.375f * (pw * ph + 1e-12f);
    float pxl = px - pw * 0.5f, pxr = px + pw * 0.5f;
    float pyt = py - ph * 0.5f, pyb = py + ph * 0.5f;

    // iou >= 0.6  <=>  inter >= 0.375*(areaP+1e-12) + 0.375*areaG
    float maxd = -1e30f;
    int win = -1;
    #pragma unroll 10
    for (int g = 0; g < NGT; ++g) {
        float4 bb = s_box[g];
        float2 tk = s_tk[g];
        float tlx = fmaxf(pxl, bb.x);
        float tly = fmaxf(pyt, bb.y);
        float brx = fminf(pxr, bb.z);
        float bry = fminf(pyb, bb.w);
        float dx = fmaxf(brx - tlx, 0.0f);
        float dy = fmaxf(bry - tly, 0.0f);
        maxd = fmaxf(maxd, fmaf(dx, dy, -tk.x));
        if (__float_as_int(tk.y) == cp) win = g;   // ascending g: last wins
    }

    float loss = 0.0f;
    bool any_v = (s_any != 0);
    if (win >= 0) {
        loss += bce_logits(r4, 1.0f);
        float4 tl = s_tl[win];
        float wv = s_wv[win];
        float d0 = r0 - tl.x, d1 = r1 - tl.y, d2 = r2 - tl.z, d3 = r3 - tl.w;
        loss += 0.5f * wv * (d0 * d0 + d1 * d1 + d2 * d2 + d3 * d3);
    } else if (!any_v || maxd < base) {
        loss += bce_logits(r4, 0.0f);
    }

    // ---------------- class BCE on prefetched value -------------------------
    if (cd1) loss += bce_logits(cv1, ct1);

    // ---------------- block reduction -> partial ----------------------------
    for (int off = 32; off > 0; off >>= 1)
        loss += __shfl_down(loss, off, 64);
    if ((tid & 63) == 0) swave[tid >> 6] = loss;
    __syncthreads();
    if (tid == 0)
        partials[b * MAIN_BLOCKS + blockIdx.x] =
            swave[0] + swave[1] + swave[2] + swave[3];
}

// Sum the per-block partials (n may exceed 256) and store the scalar output.
__global__ __launch_bounds__(256) void fcos_reduce(
        const float* __restrict__ partials, float* __restrict__ out, int n) {
    int t = threadIdx.x;
    float v = 0.0f;
    for (int i = t; i < n; i += 256) v += partials[i];
    for (int off = 32; off > 0; off >>= 1)
        v += __shfl_down(v, off, 64);
    __shared__ float sw[4];
    if ((t & 63) == 0) sw[t >> 6] = v;
    __syncthreads();
    if (t == 0) out[0] = sw[0] + sw[1] + sw[2] + sw[3];
}

extern "C" void kernel_launch(void* const* d_in, const int* in_sizes, int n_in,
                              void* d_out, int out_size, void* d_ws, size_t ws_size,
                              hipStream_t stream) {
    const float* raw            = (const float*)d_in[0];
    const float* labels         = (const float*)d_in[1];
    const float* all_anchors    = (const float*)d_in[2];
    const int*   anchor_indices = (const int*)d_in[3];
    const int*   img_size       = (const int*)d_in[4];
    float* out = (float*)d_out;

    int nB = in_sizes[0] / (NA * NCH * NG * NG);   // 16
    float* partials = (float*)d_ws;
    int nPart = nB * MAIN_BLOCKS;                  // 768

    fcos_fused<<<dim3(MAIN_BLOCKS, nB), 256, 0, stream>>>(
        raw, labels, all_anchors, anchor_indices, img_size, partials);
    fcos_reduce<<<1, 256, 0, stream>>>(partials, out, nPart);
}